// Round 3
// baseline (12833.452 us; speedup 1.0000x reference)
//
#include <hip/hip_runtime.h>

typedef unsigned short ushort_t;
typedef __attribute__((ext_vector_type(8))) __bf16 bf16x8;
typedef __attribute__((ext_vector_type(4))) float f32x4;

#define B 256
#define TENC 512
#define TDEC 64
#define DIN 64
#define HD 512
#define OD 512
#define GG 128          // workgroups in recurrent kernel
#define KTOT 576        // 512 (h) + 64 (x)
#define KI 18           // K iters of 32
#define NT 512          // threads per block
#define WPAD 584        // Wc row pitch (elements), 16B-aligned

__device__ __forceinline__ float b2f(ushort_t v) {
  union { unsigned u; float f; } x; x.u = ((unsigned)v) << 16; return x.f;
}
__device__ __forceinline__ ushort_t f2b(float f) {
  union { float f; unsigned u; } x; x.f = f;
  unsigned r = x.u + 0x7fffu + ((x.u >> 16) & 1u);   // RNE
  return (ushort_t)(r >> 16);
}
__device__ __forceinline__ float sigmf(float x) { return 1.f / (1.f + __expf(-x)); }
__device__ __forceinline__ float tanhf_fast(float x) {
  float e = __expf(2.f * x);
  return 1.f - 2.f / (e + 1.f);
}
// element load that works for either input dtype
__device__ __forceinline__ float ld_elem(const void* p, size_t i, bool f32) {
  return f32 ? ((const float*)p)[i] : b2f(((const ushort_t*)p)[i]);
}
// 8 contiguous fp32 -> bf16x8 (RNE)
__device__ __forceinline__ bf16x8 cvt8(const float* f) {
  f32x4 u = *(const f32x4*)f, v = *(const f32x4*)(f + 4);
  bf16x8 r;
  r[0] = (__bf16)u[0]; r[1] = (__bf16)u[1]; r[2] = (__bf16)u[2]; r[3] = (__bf16)u[3];
  r[4] = (__bf16)v[0]; r[5] = (__bf16)v[1]; r[6] = (__bf16)v[2]; r[7] = (__bf16)v[3];
  return r;
}

// ---------------------------------------------------------------------------
// Dtype probe: view enc_Whh (|w| <= 0.045 in either dtype) as bf16 ushorts.
// If the buffer is really fp32, low halves are random mantissa bits -> some
// |v| >= 1 (or NaN) with probability 1 - 2^-64. flag=1 means fp32 inputs.
// ---------------------------------------------------------------------------
__global__ void detect(const ushort_t* w, unsigned* flag) {
  if (threadIdx.x == 0) {
    unsigned f = 0;
    for (int i = 0; i < 128; ++i) {
      float v = b2f(w[i]);
      if (!(v * v < 1.f)) f = 1;    // catches NaN too
    }
    *flag = f;
  }
}

// ---------------------------------------------------------------------------
// Recurrent kernel: 128 WGs, WG j owns hidden units [4j, 4j+4) (16 gate cols).
// Weights LDS-resident (bf16); B-frags + A-frags in VGPRs; internal h
// ping-pong is always bf16. Grid barrier per step (monotonic counter).
// ---------------------------------------------------------------------------
__global__ __launch_bounds__(NT, 2) void lstm_seq(
    const void* enc_inp, const void* dec_inp,
    const void* eWih, const void* eWhh, const void* ebih, const void* ebhh,
    const void* dWih, const void* dWhh, const void* dbih, const void* dbhh,
    ushort_t* hbuf0, ushort_t* hbuf1, unsigned* bar,
    void* dout, const unsigned* mode)
{
  __shared__ __align__(16) ushort_t Wc[16][WPAD];      // [gate*4+unit][k] 18.7 KB
  __shared__ __align__(16) float Zb[B][17];            // z exchange       17.4 KB
  __shared__ __align__(16) float Cst[B][4];            // cell state fp32   4 KB
  __shared__ float Bias[16];

  const bool f32m = (*mode != 0);
  char* hid = (char*)dout + (size_t)B * TDEC * OD * (f32m ? 4 : 2);

  const int tid = threadIdx.x;
  const int lane = tid & 63;
  const int w = tid >> 6;          // wave w owns batch rows [32w, 32w+32)
  const int u0 = blockIdx.x * 4;
  const int fm = lane & 15;
  const int q = lane >> 4;

  for (int i = tid; i < B * 4; i += NT) ((float*)Cst)[i] = 0.f;

  bf16x8 bfrag[KI];
  unsigned bstep = 0;

  for (int phase = 0; phase < 2; ++phase) {
    const void* Wih = phase ? dWih : eWih;
    const void* Whh = phase ? dWhh : eWhh;
    const void* bih = phase ? dbih : ebih;
    const void* bhh = phase ? dbhh : ebhh;
    const void* xin = phase ? dec_inp : enc_inp;
    const int T = phase ? TDEC : TENC;
    const int xstr = phase ? (TDEC * DIN) : (TENC * DIN);   // elements

    __syncthreads();
    // this WG's 16 weight rows: row n -> gate (n>>2), unit u0+(n&3)
    for (int idx = tid; idx < 16 * KTOT; idx += NT) {
      int n = idx / KTOT, k = idx - n * KTOT;
      int grow = (n >> 2) * HD + u0 + (n & 3);
      float wv = (k < HD) ? ld_elem(Whh, (size_t)grow * HD + k, f32m)
                          : ld_elem(Wih, (size_t)grow * DIN + (k - HD), f32m);
      Wc[n][k] = f2b(wv);
    }
    if (tid < 16) {
      int grow = (tid >> 2) * HD + u0 + (tid & 3);
      Bias[tid] = ld_elem(bih, grow, f32m) + ld_elem(bhh, grow, f32m);
    }
    __syncthreads();
    // B fragments (stable for the whole phase): B[k][n] = Wc[n][k]
#pragma unroll
    for (int i = 0; i < KI; ++i)
      bfrag[i] = *(const bf16x8*)&Wc[fm][i * 32 + q * 8];

    for (int t = 0; t < T; ++t) {
      const ushort_t* hcur = (bstep & 1) ? hbuf1 : hbuf0;
      ushort_t* hnxt = (bstep & 1) ? hbuf0 : hbuf1;

      f32x4 acc0 = {0.f, 0.f, 0.f, 0.f}, acc1 = {0.f, 0.f, 0.f, 0.f};

      // h part (k = 0..511): internal bf16, mode-independent
      const ushort_t* h0p = hcur + (w * 32 + fm) * HD;
      const ushort_t* h1p = hcur + (w * 32 + 16 + fm) * HD;
#pragma unroll
      for (int i = 0; i < 16; ++i) {
        int ko = i * 32 + q * 8;
        bf16x8 a0 = *(const bf16x8*)(h0p + ko);
        bf16x8 a1 = *(const bf16x8*)(h1p + ko);
        acc0 = __builtin_amdgcn_mfma_f32_16x16x32_bf16(a0, bfrag[i], acc0, 0, 0, 0);
        acc1 = __builtin_amdgcn_mfma_f32_16x16x32_bf16(a1, bfrag[i], acc1, 0, 0, 0);
      }
      // x part (k = 512..575): input dtype depends on mode
      if (!f32m) {
        const ushort_t* x0 = (const ushort_t*)xin + (size_t)(w * 32 + fm) * xstr + t * DIN;
        const ushort_t* x1 = (const ushort_t*)xin + (size_t)(w * 32 + 16 + fm) * xstr + t * DIN;
#pragma unroll
        for (int i = 16; i < KI; ++i) {
          int xo = (i - 16) * 32 + q * 8;
          bf16x8 a0 = *(const bf16x8*)(x0 + xo);
          bf16x8 a1 = *(const bf16x8*)(x1 + xo);
          acc0 = __builtin_amdgcn_mfma_f32_16x16x32_bf16(a0, bfrag[i], acc0, 0, 0, 0);
          acc1 = __builtin_amdgcn_mfma_f32_16x16x32_bf16(a1, bfrag[i], acc1, 0, 0, 0);
        }
      } else {
        const float* x0 = (const float*)xin + (size_t)(w * 32 + fm) * xstr + t * DIN;
        const float* x1 = (const float*)xin + (size_t)(w * 32 + 16 + fm) * xstr + t * DIN;
#pragma unroll
        for (int i = 16; i < KI; ++i) {
          int xo = (i - 16) * 32 + q * 8;
          bf16x8 a0 = cvt8(x0 + xo);
          bf16x8 a1 = cvt8(x1 + xo);
          acc0 = __builtin_amdgcn_mfma_f32_16x16x32_bf16(a0, bfrag[i], acc0, 0, 0, 0);
          acc1 = __builtin_amdgcn_mfma_f32_16x16x32_bf16(a1, bfrag[i], acc1, 0, 0, 0);
        }
      }

      // z -> LDS (wave-local rows); C/D layout: col=lane&15, row=q*4+r
#pragma unroll
      for (int r = 0; r < 4; ++r) {
        Zb[w * 32 + q * 4 + r][fm] = acc0[r];
        Zb[w * 32 + 16 + q * 4 + r][fm] = acc1[r];
      }
      // cell update: 128 (b,u) pairs per wave, 2 per lane (wave-local rows)
#pragma unroll
      for (int p = 0; p < 2; ++p) {
        int idx = lane * 2 + p;       // 0..127
        int bl = idx >> 2, u = idx & 3;
        int row = w * 32 + bl;
        float zi = Zb[row][u] + Bias[u];
        float zf = Zb[row][4 + u] + Bias[4 + u];
        float zg = Zb[row][8 + u] + Bias[8 + u];
        float zo = Zb[row][12 + u] + Bias[12 + u];
        float c = Cst[row][u];
        float c2 = sigmf(zf) * c + sigmf(zi) * tanhf_fast(zg);
        float h2 = sigmf(zo) * tanhf_fast(c2);
        Cst[row][u] = c2;
        hnxt[row * HD + u0 + u] = f2b(h2);
        if (phase) {
          size_t off = ((size_t)row * TDEC + t) * HD + u0 + u;
          if (f32m) ((float*)hid)[off] = h2;
          else      ((ushort_t*)hid)[off] = f2b(h2);
        }
      }

      // grid barrier (monotonic counter, release/acquire at agent scope)
      __syncthreads();                 // all waves' stores drained (vmcnt 0)
      if (tid == 0) {
        __threadfence();
        __hip_atomic_fetch_add(bar, 1u, __ATOMIC_RELEASE, __HIP_MEMORY_SCOPE_AGENT);
        unsigned tgt = (unsigned)GG * (bstep + 1);
        while (__hip_atomic_load(bar, __ATOMIC_ACQUIRE, __HIP_MEMORY_SCOPE_AGENT) < tgt)
          __builtin_amdgcn_s_sleep(2);
        __threadfence();
      }
      __syncthreads();
      ++bstep;
    }
  }
}

// ---------------------------------------------------------------------------
// Output projection: Y[16384x512] = Hd[16384x512] @ out_W^T + out_b.
// Hd/Y dtype follows mode; B-frags in VGPRs.
// ---------------------------------------------------------------------------
__global__ __launch_bounds__(NT, 2) void out_proj(
    const void* Wo, const void* bo, void* dout, const unsigned* mode)
{
  __shared__ __align__(16) ushort_t Wc[16][520];
  const bool f32m = (*mode != 0);
  char* Ybase = (char*)dout;
  const char* Hd = Ybase + (size_t)B * TDEC * OD * (f32m ? 4 : 2);

  const int tid = threadIdx.x, lane = tid & 63, w = tid >> 6;
  const int fm = lane & 15, q = lane >> 4;
  const int nb = blockIdx.x & 31, mb = blockIdx.x >> 5;
  const int m0 = mb * 256, n0 = nb * 16;

  for (int idx = tid; idx < 16 * 512; idx += NT) {
    int n = idx >> 9, k = idx & 511;
    Wc[n][k] = f2b(ld_elem(Wo, (size_t)(n0 + n) * 512 + k, f32m));
  }
  __syncthreads();
  bf16x8 bfrag[16];
#pragma unroll
  for (int i = 0; i < 16; ++i) bfrag[i] = *(const bf16x8*)&Wc[fm][i * 32 + q * 8];

  f32x4 acc0 = {0.f, 0.f, 0.f, 0.f}, acc1 = {0.f, 0.f, 0.f, 0.f};
  if (!f32m) {
    const ushort_t* a0p = (const ushort_t*)Hd + (size_t)(m0 + w * 32 + fm) * 512;
    const ushort_t* a1p = (const ushort_t*)Hd + (size_t)(m0 + w * 32 + 16 + fm) * 512;
#pragma unroll
    for (int i = 0; i < 16; ++i) {
      int ko = i * 32 + q * 8;
      bf16x8 a0 = *(const bf16x8*)(a0p + ko);
      bf16x8 a1 = *(const bf16x8*)(a1p + ko);
      acc0 = __builtin_amdgcn_mfma_f32_16x16x32_bf16(a0, bfrag[i], acc0, 0, 0, 0);
      acc1 = __builtin_amdgcn_mfma_f32_16x16x32_bf16(a1, bfrag[i], acc1, 0, 0, 0);
    }
  } else {
    const float* a0p = (const float*)Hd + (size_t)(m0 + w * 32 + fm) * 512;
    const float* a1p = (const float*)Hd + (size_t)(m0 + w * 32 + 16 + fm) * 512;
#pragma unroll
    for (int i = 0; i < 16; ++i) {
      int ko = i * 32 + q * 8;
      bf16x8 a0 = cvt8(a0p + ko);
      bf16x8 a1 = cvt8(a1p + ko);
      acc0 = __builtin_amdgcn_mfma_f32_16x16x32_bf16(a0, bfrag[i], acc0, 0, 0, 0);
      acc1 = __builtin_amdgcn_mfma_f32_16x16x32_bf16(a1, bfrag[i], acc1, 0, 0, 0);
    }
  }
  float bias = ld_elem(bo, n0 + fm, f32m);
#pragma unroll
  for (int r = 0; r < 4; ++r) {
    size_t off0 = (size_t)(m0 + w * 32 + q * 4 + r) * 512 + n0 + fm;
    size_t off1 = off0 + (size_t)16 * 512;
    float v0 = acc0[r] + bias, v1 = acc1[r] + bias;
    if (f32m) { ((float*)Ybase)[off0] = v0; ((float*)Ybase)[off1] = v1; }
    else      { ((ushort_t*)Ybase)[off0] = f2b(v0); ((ushort_t*)Ybase)[off1] = f2b(v1); }
  }
}

extern "C" void kernel_launch(void* const* d_in, const int* in_sizes, int n_in,
                              void* d_out, int out_size, void* d_ws, size_t ws_size,
                              hipStream_t stream) {
  (void)in_sizes; (void)n_in; (void)out_size; (void)ws_size;
  const void* enc_inp = d_in[0];
  const void* dec_inp = d_in[1];
  const void* eWih = d_in[2];
  const void* eWhh = d_in[3];
  const void* ebih = d_in[4];
  const void* ebhh = d_in[5];
  const void* dWih = d_in[6];
  const void* dWhh = d_in[7];
  const void* dbih = d_in[8];
  const void* dbhh = d_in[9];
  const void* outW = d_in[10];
  const void* outb = d_in[11];

  unsigned* flag = (unsigned*)d_ws;

  // scratch inside the dec_outputs region of d_out (overwritten by out_proj):
  // fixed BYTE offsets valid for both dtypes (region >= 16.8 MB).
  char* ob = (char*)d_out;
  unsigned* bar = (unsigned*)ob;                        // 4 B at offset 0
  ushort_t* hbuf0 = (ushort_t*)(ob + 1024);             // 256 KB (always bf16)
  ushort_t* hbuf1 = (ushort_t*)(ob + 1024 + (size_t)B * HD * 2);

  // zero barrier counter + hbuf0 (initial h); hbuf1 fully written at step 0
  hipMemsetAsync(d_out, 0, 1024 + (size_t)B * HD * 2, stream);

  detect<<<1, 64, 0, stream>>>((const ushort_t*)eWhh, flag);
  lstm_seq<<<GG, NT, 0, stream>>>(enc_inp, dec_inp, eWih, eWhh, ebih, ebhh,
                                  dWih, dWhh, dbih, dbhh,
                                  hbuf0, hbuf1, bar, d_out, flag);
  out_proj<<<dim3(64 * 32), NT, 0, stream>>>(outW, outb, d_out, flag);
}

// Round 4
// 10983.831 us; speedup vs baseline: 1.1684x; 1.1684x over previous
//
#include <hip/hip_runtime.h>

typedef unsigned short ushort_t;
typedef unsigned long long u64;
typedef __attribute__((ext_vector_type(8))) __bf16 bf16x8;
typedef __attribute__((ext_vector_type(4))) float f32x4;

#define B 256
#define TENC 512
#define TDEC 64
#define DIN 64
#define HD 512
#define OD 512
#define GG 128          // workgroups in recurrent kernel
#define KTOT 576        // 512 (h) + 64 (x)
#define KI 18           // K iters of 32
#define NT 512          // threads per block
#define WPAD 584        // Wc row pitch (elements), 16B-aligned

__device__ __forceinline__ float b2f(ushort_t v) {
  union { unsigned u; float f; } x; x.u = ((unsigned)v) << 16; return x.f;
}
__device__ __forceinline__ ushort_t f2b(float f) {
  union { float f; unsigned u; } x; x.f = f;
  unsigned r = x.u + 0x7fffu + ((x.u >> 16) & 1u);   // RNE
  return (ushort_t)(r >> 16);
}
__device__ __forceinline__ float sigmf(float x) { return 1.f / (1.f + __expf(-x)); }
__device__ __forceinline__ float tanhf_fast(float x) {
  float e = __expf(2.f * x);
  return 1.f - 2.f / (e + 1.f);
}
__device__ __forceinline__ float ld_elem(const void* p, size_t i, bool f32) {
  return f32 ? ((const float*)p)[i] : b2f(((const ushort_t*)p)[i]);
}
__device__ __forceinline__ bf16x8 cvt8(const float* f) {
  f32x4 u = *(const f32x4*)f, v = *(const f32x4*)(f + 4);
  bf16x8 r;
  r[0] = (__bf16)u[0]; r[1] = (__bf16)u[1]; r[2] = (__bf16)u[2]; r[3] = (__bf16)u[3];
  r[4] = (__bf16)v[0]; r[5] = (__bf16)v[1]; r[6] = (__bf16)v[2]; r[7] = (__bf16)v[3];
  return r;
}
// 16B device-coherent h load: two relaxed agent-scope u64 atomics (sc1, no
// cache maintenance). Compiler manages waitcnt.
__device__ __forceinline__ bf16x8 ld_h16(const ushort_t* p) {
  union { u64 q[2]; bf16x8 v; } x;
  x.q[0] = __hip_atomic_load((const u64*)p,     __ATOMIC_RELAXED, __HIP_MEMORY_SCOPE_AGENT);
  x.q[1] = __hip_atomic_load((const u64*)p + 1, __ATOMIC_RELAXED, __HIP_MEMORY_SCOPE_AGENT);
  return x.v;
}

// ---------------------------------------------------------------------------
// Dtype probe (fp32 vs bf16 inputs) -> flag in d_ws.
// ---------------------------------------------------------------------------
__global__ void detect(const ushort_t* w, unsigned* flag) {
  if (threadIdx.x == 0) {
    unsigned f = 0;
    for (int i = 0; i < 128; ++i) {
      float v = b2f(w[i]);
      if (!(v * v < 1.f)) f = 1;    // catches NaN too
    }
    *flag = f;
  }
}

// ---------------------------------------------------------------------------
// Recurrent kernel: 128 WGs, WG j owns hidden units [4j, 4j+4) (16 gate cols).
// Weights LDS->VGPR resident; h ping-pong exchanged via device-scope (sc1)
// relaxed atomics — NO cache-wide fences anywhere. Grid barrier = relaxed
// monotonic counter in LLC.
// ---------------------------------------------------------------------------
__global__ __launch_bounds__(NT, 2) void lstm_seq(
    const void* enc_inp, const void* dec_inp,
    const void* eWih, const void* eWhh, const void* ebih, const void* ebhh,
    const void* dWih, const void* dWhh, const void* dbih, const void* dbhh,
    ushort_t* hbuf0, ushort_t* hbuf1, unsigned* bar,
    void* dout, const unsigned* mode)
{
  __shared__ __align__(16) ushort_t Wc[16][WPAD];      // 18.7 KB
  __shared__ __align__(16) float Zb[B][17];            // 17.4 KB
  __shared__ __align__(16) float Cst[B][4];            //  4 KB
  __shared__ float Bias[16];

  const bool f32m = (*mode != 0);
  char* hid = (char*)dout + (size_t)B * TDEC * OD * (f32m ? 4 : 2);

  const int tid = threadIdx.x;
  const int lane = tid & 63;
  const int w = tid >> 6;          // wave w owns batch rows [32w, 32w+32)
  const int u0 = blockIdx.x * 4;
  const int fm = lane & 15;
  const int q = lane >> 4;

  for (int i = tid; i < B * 4; i += NT) ((float*)Cst)[i] = 0.f;

  bf16x8 bfrag[KI];
  unsigned bstep = 0;

  for (int phase = 0; phase < 2; ++phase) {
    const void* Wih = phase ? dWih : eWih;
    const void* Whh = phase ? dWhh : eWhh;
    const void* bih = phase ? dbih : ebih;
    const void* bhh = phase ? dbhh : ebhh;
    const void* xin = phase ? dec_inp : enc_inp;
    const int T = phase ? TDEC : TENC;
    const int xstr = phase ? (TDEC * DIN) : (TENC * DIN);   // elements

    __syncthreads();
    for (int idx = tid; idx < 16 * KTOT; idx += NT) {
      int n = idx / KTOT, k = idx - n * KTOT;
      int grow = (n >> 2) * HD + u0 + (n & 3);
      float wv = (k < HD) ? ld_elem(Whh, (size_t)grow * HD + k, f32m)
                          : ld_elem(Wih, (size_t)grow * DIN + (k - HD), f32m);
      Wc[n][k] = f2b(wv);
    }
    if (tid < 16) {
      int grow = (tid >> 2) * HD + u0 + (tid & 3);
      Bias[tid] = ld_elem(bih, grow, f32m) + ld_elem(bhh, grow, f32m);
    }
    __syncthreads();
#pragma unroll
    for (int i = 0; i < KI; ++i)
      bfrag[i] = *(const bf16x8*)&Wc[fm][i * 32 + q * 8];

    for (int t = 0; t < T; ++t) {
      const ushort_t* hcur = (bstep & 1) ? hbuf1 : hbuf0;
      ushort_t* hnxt = (bstep & 1) ? hbuf0 : hbuf1;

      // ---- issue ALL h loads first (coherent sc1, ~64 outstanding) ----
      const ushort_t* h0p = hcur + (w * 32 + fm) * HD;
      const ushort_t* h1p = hcur + (w * 32 + 16 + fm) * HD;
      bf16x8 ah0[16], ah1[16];
#pragma unroll
      for (int i = 0; i < 16; ++i) {
        ah0[i] = ld_h16(h0p + i * 32 + q * 8);
        ah1[i] = ld_h16(h1p + i * 32 + q * 8);
      }

      f32x4 acc0 = {0.f, 0.f, 0.f, 0.f}, acc1 = {0.f, 0.f, 0.f, 0.f};
#pragma unroll
      for (int i = 0; i < 16; ++i) {
        acc0 = __builtin_amdgcn_mfma_f32_16x16x32_bf16(ah0[i], bfrag[i], acc0, 0, 0, 0);
        acc1 = __builtin_amdgcn_mfma_f32_16x16x32_bf16(ah1[i], bfrag[i], acc1, 0, 0, 0);
      }
      // x part (k = 512..575): read-only input, normal cached loads
      if (!f32m) {
        const ushort_t* x0 = (const ushort_t*)xin + (size_t)(w * 32 + fm) * xstr + t * DIN;
        const ushort_t* x1 = (const ushort_t*)xin + (size_t)(w * 32 + 16 + fm) * xstr + t * DIN;
#pragma unroll
        for (int i = 16; i < KI; ++i) {
          int xo = (i - 16) * 32 + q * 8;
          bf16x8 a0 = *(const bf16x8*)(x0 + xo);
          bf16x8 a1 = *(const bf16x8*)(x1 + xo);
          acc0 = __builtin_amdgcn_mfma_f32_16x16x32_bf16(a0, bfrag[i], acc0, 0, 0, 0);
          acc1 = __builtin_amdgcn_mfma_f32_16x16x32_bf16(a1, bfrag[i], acc1, 0, 0, 0);
        }
      } else {
        const float* x0 = (const float*)xin + (size_t)(w * 32 + fm) * xstr + t * DIN;
        const float* x1 = (const float*)xin + (size_t)(w * 32 + 16 + fm) * xstr + t * DIN;
#pragma unroll
        for (int i = 16; i < KI; ++i) {
          int xo = (i - 16) * 32 + q * 8;
          bf16x8 a0 = cvt8(x0 + xo);
          bf16x8 a1 = cvt8(x1 + xo);
          acc0 = __builtin_amdgcn_mfma_f32_16x16x32_bf16(a0, bfrag[i], acc0, 0, 0, 0);
          acc1 = __builtin_amdgcn_mfma_f32_16x16x32_bf16(a1, bfrag[i], acc1, 0, 0, 0);
        }
      }

      // z -> LDS (wave-local rows); C/D layout: col=lane&15, row=q*4+r
#pragma unroll
      for (int r = 0; r < 4; ++r) {
        Zb[w * 32 + q * 4 + r][fm] = acc0[r];
        Zb[w * 32 + 16 + q * 4 + r][fm] = acc1[r];
      }
      // cell update: each lane handles 2 consecutive (b,u) pairs = 1 uint
      {
        int idx0 = lane * 2;
        int bl = idx0 >> 2, ub = idx0 & 3;       // ub in {0, 2}
        int row = w * 32 + bl;
        float h2v[2];
#pragma unroll
        for (int p = 0; p < 2; ++p) {
          int u = ub + p;
          float zi = Zb[row][u] + Bias[u];
          float zf = Zb[row][4 + u] + Bias[4 + u];
          float zg = Zb[row][8 + u] + Bias[8 + u];
          float zo = Zb[row][12 + u] + Bias[12 + u];
          float c = Cst[row][u];
          float c2 = sigmf(zf) * c + sigmf(zi) * tanhf_fast(zg);
          h2v[p] = sigmf(zo) * tanhf_fast(c2);
          Cst[row][u] = c2;
        }
        unsigned pk = (unsigned)f2b(h2v[0]) | ((unsigned)f2b(h2v[1]) << 16);
        // device-coherent write-through (sc1), no fence needed
        __hip_atomic_store((unsigned*)(hnxt + row * HD + u0 + ub), pk,
                           __ATOMIC_RELAXED, __HIP_MEMORY_SCOPE_AGENT);
        if (phase) {
          size_t off = ((size_t)row * TDEC + t) * HD + u0 + ub;
          if (f32m) {
            float2 f2; f2.x = h2v[0]; f2.y = h2v[1];
            *(float2*)((float*)hid + off) = f2;      // normal store; kernel-boundary flush
          } else {
            *(unsigned*)((ushort_t*)hid + off) = pk;
          }
        }
      }

      // grid barrier: relaxed monotonic counter, NO cache-maintenance ops
      __syncthreads();                 // drains each wave's stores (vmcnt 0)
      if (tid == 0) {
        asm volatile("" ::: "memory");
        __hip_atomic_fetch_add(bar, 1u, __ATOMIC_RELAXED, __HIP_MEMORY_SCOPE_AGENT);
        unsigned tgt = (unsigned)GG * (bstep + 1);
        while (__hip_atomic_load(bar, __ATOMIC_RELAXED, __HIP_MEMORY_SCOPE_AGENT) < tgt)
          __builtin_amdgcn_s_sleep(1);
        asm volatile("" ::: "memory");
      }
      __syncthreads();
      ++bstep;
    }
  }
}

// ---------------------------------------------------------------------------
// Output projection: Y[16384x512] = Hd[16384x512] @ out_W^T + out_b.
// ---------------------------------------------------------------------------
__global__ __launch_bounds__(NT, 2) void out_proj(
    const void* Wo, const void* bo, void* dout, const unsigned* mode)
{
  __shared__ __align__(16) ushort_t Wc[16][520];
  const bool f32m = (*mode != 0);
  char* Ybase = (char*)dout;
  const char* Hd = Ybase + (size_t)B * TDEC * OD * (f32m ? 4 : 2);

  const int tid = threadIdx.x, lane = tid & 63, w = tid >> 6;
  const int fm = lane & 15, q = lane >> 4;
  const int nb = blockIdx.x & 31, mb = blockIdx.x >> 5;
  const int m0 = mb * 256, n0 = nb * 16;

  for (int idx = tid; idx < 16 * 512; idx += NT) {
    int n = idx >> 9, k = idx & 511;
    Wc[n][k] = f2b(ld_elem(Wo, (size_t)(n0 + n) * 512 + k, f32m));
  }
  __syncthreads();
  bf16x8 bfrag[16];
#pragma unroll
  for (int i = 0; i < 16; ++i) bfrag[i] = *(const bf16x8*)&Wc[fm][i * 32 + q * 8];

  f32x4 acc0 = {0.f, 0.f, 0.f, 0.f}, acc1 = {0.f, 0.f, 0.f, 0.f};
  if (!f32m) {
    const ushort_t* a0p = (const ushort_t*)Hd + (size_t)(m0 + w * 32 + fm) * 512;
    const ushort_t* a1p = (const ushort_t*)Hd + (size_t)(m0 + w * 32 + 16 + fm) * 512;
#pragma unroll
    for (int i = 0; i < 16; ++i) {
      int ko = i * 32 + q * 8;
      bf16x8 a0 = *(const bf16x8*)(a0p + ko);
      bf16x8 a1 = *(const bf16x8*)(a1p + ko);
      acc0 = __builtin_amdgcn_mfma_f32_16x16x32_bf16(a0, bfrag[i], acc0, 0, 0, 0);
      acc1 = __builtin_amdgcn_mfma_f32_16x16x32_bf16(a1, bfrag[i], acc1, 0, 0, 0);
    }
  } else {
    const float* a0p = (const float*)Hd + (size_t)(m0 + w * 32 + fm) * 512;
    const float* a1p = (const float*)Hd + (size_t)(m0 + w * 32 + 16 + fm) * 512;
#pragma unroll
    for (int i = 0; i < 16; ++i) {
      int ko = i * 32 + q * 8;
      bf16x8 a0 = cvt8(a0p + ko);
      bf16x8 a1 = cvt8(a1p + ko);
      acc0 = __builtin_amdgcn_mfma_f32_16x16x32_bf16(a0, bfrag[i], acc0, 0, 0, 0);
      acc1 = __builtin_amdgcn_mfma_f32_16x16x32_bf16(a1, bfrag[i], acc1, 0, 0, 0);
    }
  }
  float bias = ld_elem(bo, n0 + fm, f32m);
#pragma unroll
  for (int r = 0; r < 4; ++r) {
    size_t off0 = (size_t)(m0 + w * 32 + q * 4 + r) * 512 + n0 + fm;
    size_t off1 = off0 + (size_t)16 * 512;
    float v0 = acc0[r] + bias, v1 = acc1[r] + bias;
    if (f32m) { ((float*)Ybase)[off0] = v0; ((float*)Ybase)[off1] = v1; }
    else      { ((ushort_t*)Ybase)[off0] = f2b(v0); ((ushort_t*)Ybase)[off1] = f2b(v1); }
  }
}

extern "C" void kernel_launch(void* const* d_in, const int* in_sizes, int n_in,
                              void* d_out, int out_size, void* d_ws, size_t ws_size,
                              hipStream_t stream) {
  (void)in_sizes; (void)n_in; (void)out_size; (void)ws_size;
  const void* enc_inp = d_in[0];
  const void* dec_inp = d_in[1];
  const void* eWih = d_in[2];
  const void* eWhh = d_in[3];
  const void* ebih = d_in[4];
  const void* ebhh = d_in[5];
  const void* dWih = d_in[6];
  const void* dWhh = d_in[7];
  const void* dbih = d_in[8];
  const void* dbhh = d_in[9];
  const void* outW = d_in[10];
  const void* outb = d_in[11];

  unsigned* flag = (unsigned*)d_ws;

  // scratch inside the dec_outputs region of d_out (overwritten by out_proj)
  char* ob = (char*)d_out;
  unsigned* bar = (unsigned*)ob;                        // 4 B at offset 0
  ushort_t* hbuf0 = (ushort_t*)(ob + 1024);             // 256 KB (always bf16)
  ushort_t* hbuf1 = (ushort_t*)(ob + 1024 + (size_t)B * HD * 2);

  hipMemsetAsync(d_out, 0, 1024 + (size_t)B * HD * 2, stream);

  detect<<<1, 64, 0, stream>>>((const ushort_t*)eWhh, flag);
  lstm_seq<<<GG, NT, 0, stream>>>(enc_inp, dec_inp, eWih, eWhh, ebih, ebhh,
                                  dWih, dWhh, dbih, dbhh,
                                  hbuf0, hbuf1, bar, d_out, flag);
  out_proj<<<dim3(64 * 32), NT, 0, stream>>>(outW, outb, d_out, flag);
}

// Round 5
// 10457.964 us; speedup vs baseline: 1.2271x; 1.0503x over previous
//
#include <hip/hip_runtime.h>

typedef unsigned short ushort_t;
typedef unsigned long long u64;
typedef __attribute__((ext_vector_type(8))) __bf16 bf16x8;
typedef __attribute__((ext_vector_type(4))) float f32x4;

#define B 256
#define TENC 512
#define TDEC 64
#define DIN 64
#define HD 512
#define OD 512
#define GG 128          // workgroups in recurrent kernel
#define KTOT 576        // 512 (h) + 64 (x)
#define KI 18           // K iters of 32
#define NT 512          // threads per block
#define WPAD 584        // Wc row pitch (elements), 16B-aligned

__device__ __forceinline__ float b2f(ushort_t v) {
  union { unsigned u; float f; } x; x.u = ((unsigned)v) << 16; return x.f;
}
__device__ __forceinline__ ushort_t f2b(float f) {
  union { float f; unsigned u; } x; x.f = f;
  unsigned r = x.u + 0x7fffu + ((x.u >> 16) & 1u);   // RNE
  return (ushort_t)(r >> 16);
}
__device__ __forceinline__ float sigmf(float x) { return 1.f / (1.f + __expf(-x)); }
__device__ __forceinline__ float tanhf_fast(float x) {
  float e = __expf(2.f * x);
  return 1.f - 2.f / (e + 1.f);
}
__device__ __forceinline__ float ld_elem(const void* p, size_t i, bool f32) {
  return f32 ? ((const float*)p)[i] : b2f(((const ushort_t*)p)[i]);
}
__device__ __forceinline__ bf16x8 cvt8(const float* f) {
  f32x4 u = *(const f32x4*)f, v = *(const f32x4*)(f + 4);
  bf16x8 r;
  r[0] = (__bf16)u[0]; r[1] = (__bf16)u[1]; r[2] = (__bf16)u[2]; r[3] = (__bf16)u[3];
  r[4] = (__bf16)v[0]; r[5] = (__bf16)v[1]; r[6] = (__bf16)v[2]; r[7] = (__bf16)v[3];
  return r;
}
// 16B device-coherent h load: two relaxed agent-scope u64 atomics (sc1).
__device__ __forceinline__ bf16x8 ld_h16(const ushort_t* p) {
  union { u64 q[2]; bf16x8 v; } x;
  x.q[0] = __hip_atomic_load((const u64*)p,     __ATOMIC_RELAXED, __HIP_MEMORY_SCOPE_AGENT);
  x.q[1] = __hip_atomic_load((const u64*)p + 1, __ATOMIC_RELAXED, __HIP_MEMORY_SCOPE_AGENT);
  return x.v;
}

// ---------------------------------------------------------------------------
// Dtype probe (fp32 vs bf16 inputs) -> flag in d_ws.
// ---------------------------------------------------------------------------
__global__ void detect(const ushort_t* w, unsigned* flag) {
  if (threadIdx.x == 0) {
    unsigned f = 0;
    for (int i = 0; i < 128; ++i) {
      float v = b2f(w[i]);
      if (!(v * v < 1.f)) f = 1;    // catches NaN too
    }
    *flag = f;
  }
}

// ---------------------------------------------------------------------------
// Recurrent kernel. Grid barrier = distributed per-WG flag lines (stores,
// no RMW contention) + WG0 aggregates (128 parallel polls) + go broadcast.
// ---------------------------------------------------------------------------
__global__ __launch_bounds__(NT, 2) void lstm_seq(
    const void* enc_inp, const void* dec_inp,
    const void* eWih, const void* eWhh, const void* ebih, const void* ebhh,
    const void* dWih, const void* dWhh, const void* dbih, const void* dbhh,
    ushort_t* hbuf0, ushort_t* hbuf1,
    unsigned* flags, unsigned* go,
    void* dout, const unsigned* mode)
{
  __shared__ __align__(16) ushort_t Wc[16][WPAD];      // 18.7 KB
  __shared__ __align__(16) float Zb[B][17];            // 17.4 KB
  __shared__ __align__(16) float Cst[B][4];            //  4 KB
  __shared__ float Bias[16];

  const bool f32m = (*mode != 0);
  char* hid = (char*)dout + (size_t)B * TDEC * OD * (f32m ? 4 : 2);

  const int tid = threadIdx.x;
  const int lane = tid & 63;
  const int w = tid >> 6;          // wave w owns batch rows [32w, 32w+32)
  const int wg = blockIdx.x;
  const int u0 = wg * 4;
  const int fm = lane & 15;
  const int q = lane >> 4;

  for (int i = tid; i < B * 4; i += NT) ((float*)Cst)[i] = 0.f;

  bf16x8 bfrag[KI];
  unsigned bstep = 0;

  for (int phase = 0; phase < 2; ++phase) {
    const void* Wih = phase ? dWih : eWih;
    const void* Whh = phase ? dWhh : eWhh;
    const void* bih = phase ? dbih : ebih;
    const void* bhh = phase ? dbhh : ebhh;
    const void* xin = phase ? dec_inp : enc_inp;
    const int T = phase ? TDEC : TENC;
    const int xstr = phase ? (TDEC * DIN) : (TENC * DIN);   // elements

    __syncthreads();
    for (int idx = tid; idx < 16 * KTOT; idx += NT) {
      int n = idx / KTOT, k = idx - n * KTOT;
      int grow = (n >> 2) * HD + u0 + (n & 3);
      float wv = (k < HD) ? ld_elem(Whh, (size_t)grow * HD + k, f32m)
                          : ld_elem(Wih, (size_t)grow * DIN + (k - HD), f32m);
      Wc[n][k] = f2b(wv);
    }
    if (tid < 16) {
      int grow = (tid >> 2) * HD + u0 + (tid & 3);
      Bias[tid] = ld_elem(bih, grow, f32m) + ld_elem(bhh, grow, f32m);
    }
    __syncthreads();
#pragma unroll
    for (int i = 0; i < KI; ++i)
      bfrag[i] = *(const bf16x8*)&Wc[fm][i * 32 + q * 8];

    for (int t = 0; t < T; ++t) {
      const ushort_t* hcur = (bstep & 1) ? hbuf1 : hbuf0;
      ushort_t* hnxt = (bstep & 1) ? hbuf0 : hbuf1;

      // ---- issue ALL h loads first (coherent sc1, ~64 outstanding) ----
      const ushort_t* h0p = hcur + (w * 32 + fm) * HD;
      const ushort_t* h1p = hcur + (w * 32 + 16 + fm) * HD;
      bf16x8 ah0[16], ah1[16];
#pragma unroll
      for (int i = 0; i < 16; ++i) {
        ah0[i] = ld_h16(h0p + i * 32 + q * 8);
        ah1[i] = ld_h16(h1p + i * 32 + q * 8);
      }

      f32x4 acc0 = {0.f, 0.f, 0.f, 0.f}, acc1 = {0.f, 0.f, 0.f, 0.f};
#pragma unroll
      for (int i = 0; i < 16; ++i) {
        acc0 = __builtin_amdgcn_mfma_f32_16x16x32_bf16(ah0[i], bfrag[i], acc0, 0, 0, 0);
        acc1 = __builtin_amdgcn_mfma_f32_16x16x32_bf16(ah1[i], bfrag[i], acc1, 0, 0, 0);
      }
      // x part (k = 512..575): read-only input, normal cached loads
      if (!f32m) {
        const ushort_t* x0 = (const ushort_t*)xin + (size_t)(w * 32 + fm) * xstr + t * DIN;
        const ushort_t* x1 = (const ushort_t*)xin + (size_t)(w * 32 + 16 + fm) * xstr + t * DIN;
#pragma unroll
        for (int i = 16; i < KI; ++i) {
          int xo = (i - 16) * 32 + q * 8;
          bf16x8 a0 = *(const bf16x8*)(x0 + xo);
          bf16x8 a1 = *(const bf16x8*)(x1 + xo);
          acc0 = __builtin_amdgcn_mfma_f32_16x16x32_bf16(a0, bfrag[i], acc0, 0, 0, 0);
          acc1 = __builtin_amdgcn_mfma_f32_16x16x32_bf16(a1, bfrag[i], acc1, 0, 0, 0);
        }
      } else {
        const float* x0 = (const float*)xin + (size_t)(w * 32 + fm) * xstr + t * DIN;
        const float* x1 = (const float*)xin + (size_t)(w * 32 + 16 + fm) * xstr + t * DIN;
#pragma unroll
        for (int i = 16; i < KI; ++i) {
          int xo = (i - 16) * 32 + q * 8;
          bf16x8 a0 = cvt8(x0 + xo);
          bf16x8 a1 = cvt8(x1 + xo);
          acc0 = __builtin_amdgcn_mfma_f32_16x16x32_bf16(a0, bfrag[i], acc0, 0, 0, 0);
          acc1 = __builtin_amdgcn_mfma_f32_16x16x32_bf16(a1, bfrag[i], acc1, 0, 0, 0);
        }
      }

      // z -> LDS (wave-local rows); C/D layout: col=lane&15, row=q*4+r
#pragma unroll
      for (int r = 0; r < 4; ++r) {
        Zb[w * 32 + q * 4 + r][fm] = acc0[r];
        Zb[w * 32 + 16 + q * 4 + r][fm] = acc1[r];
      }
      // cell update: each lane handles 2 consecutive (b,u) pairs = 1 uint
      {
        int idx0 = lane * 2;
        int bl = idx0 >> 2, ub = idx0 & 3;       // ub in {0, 2}
        int row = w * 32 + bl;
        float h2v[2];
#pragma unroll
        for (int p = 0; p < 2; ++p) {
          int u = ub + p;
          float zi = Zb[row][u] + Bias[u];
          float zf = Zb[row][4 + u] + Bias[4 + u];
          float zg = Zb[row][8 + u] + Bias[8 + u];
          float zo = Zb[row][12 + u] + Bias[12 + u];
          float c = Cst[row][u];
          float c2 = sigmf(zf) * c + sigmf(zi) * tanhf_fast(zg);
          h2v[p] = sigmf(zo) * tanhf_fast(c2);
          Cst[row][u] = c2;
        }
        unsigned pk = (unsigned)f2b(h2v[0]) | ((unsigned)f2b(h2v[1]) << 16);
        __hip_atomic_store((unsigned*)(hnxt + row * HD + u0 + ub), pk,
                           __ATOMIC_RELAXED, __HIP_MEMORY_SCOPE_AGENT);
        if (phase) {
          size_t off = ((size_t)row * TDEC + t) * HD + u0 + ub;
          if (f32m) {
            float2 f2; f2.x = h2v[0]; f2.y = h2v[1];
            *(float2*)((float*)hid + off) = f2;
          } else {
            *(unsigned*)((ushort_t*)hid + off) = pk;
          }
        }
      }

      // ---- grid barrier: flag stores + WG0 aggregation + go broadcast ----
      const unsigned tgt = bstep + 1;
      __syncthreads();                 // drains each wave's stores (vmcnt 0)
      if (tid == 0)
        __hip_atomic_store(&flags[wg * 32], tgt,
                           __ATOMIC_RELAXED, __HIP_MEMORY_SCOPE_AGENT);
      if (wg == 0) {
        if (tid < GG) {
          while (__hip_atomic_load(&flags[tid * 32],
                                   __ATOMIC_RELAXED, __HIP_MEMORY_SCOPE_AGENT) < tgt)
            __builtin_amdgcn_s_sleep(1);
        }
        __syncthreads();               // all 128 flags confirmed
        if (tid == 0)
          __hip_atomic_store(go, tgt, __ATOMIC_RELAXED, __HIP_MEMORY_SCOPE_AGENT);
      } else if (tid == 0) {
        while (__hip_atomic_load(go, __ATOMIC_RELAXED, __HIP_MEMORY_SCOPE_AGENT) < tgt)
          __builtin_amdgcn_s_sleep(1);
      }
      __syncthreads();
      ++bstep;
    }
  }
}

// ---------------------------------------------------------------------------
// Output projection: Y[16384x512] = Hd[16384x512] @ out_W^T + out_b.
// ---------------------------------------------------------------------------
__global__ __launch_bounds__(NT, 2) void out_proj(
    const void* Wo, const void* bo, void* dout, const unsigned* mode)
{
  __shared__ __align__(16) ushort_t Wc[16][520];
  const bool f32m = (*mode != 0);
  char* Ybase = (char*)dout;
  const char* Hd = Ybase + (size_t)B * TDEC * OD * (f32m ? 4 : 2);

  const int tid = threadIdx.x, lane = tid & 63, w = tid >> 6;
  const int fm = lane & 15, q = lane >> 4;
  const int nb = blockIdx.x & 31, mb = blockIdx.x >> 5;
  const int m0 = mb * 256, n0 = nb * 16;

  for (int idx = tid; idx < 16 * 512; idx += NT) {
    int n = idx >> 9, k = idx & 511;
    Wc[n][k] = f2b(ld_elem(Wo, (size_t)(n0 + n) * 512 + k, f32m));
  }
  __syncthreads();
  bf16x8 bfrag[16];
#pragma unroll
  for (int i = 0; i < 16; ++i) bfrag[i] = *(const bf16x8*)&Wc[fm][i * 32 + q * 8];

  f32x4 acc0 = {0.f, 0.f, 0.f, 0.f}, acc1 = {0.f, 0.f, 0.f, 0.f};
  if (!f32m) {
    const ushort_t* a0p = (const ushort_t*)Hd + (size_t)(m0 + w * 32 + fm) * 512;
    const ushort_t* a1p = (const ushort_t*)Hd + (size_t)(m0 + w * 32 + 16 + fm) * 512;
#pragma unroll
    for (int i = 0; i < 16; ++i) {
      int ko = i * 32 + q * 8;
      bf16x8 a0 = *(const bf16x8*)(a0p + ko);
      bf16x8 a1 = *(const bf16x8*)(a1p + ko);
      acc0 = __builtin_amdgcn_mfma_f32_16x16x32_bf16(a0, bfrag[i], acc0, 0, 0, 0);
      acc1 = __builtin_amdgcn_mfma_f32_16x16x32_bf16(a1, bfrag[i], acc1, 0, 0, 0);
    }
  } else {
    const float* a0p = (const float*)Hd + (size_t)(m0 + w * 32 + fm) * 512;
    const float* a1p = (const float*)Hd + (size_t)(m0 + w * 32 + 16 + fm) * 512;
#pragma unroll
    for (int i = 0; i < 16; ++i) {
      int ko = i * 32 + q * 8;
      bf16x8 a0 = cvt8(a0p + ko);
      bf16x8 a1 = cvt8(a1p + ko);
      acc0 = __builtin_amdgcn_mfma_f32_16x16x32_bf16(a0, bfrag[i], acc0, 0, 0, 0);
      acc1 = __builtin_amdgcn_mfma_f32_16x16x32_bf16(a1, bfrag[i], acc1, 0, 0, 0);
    }
  }
  float bias = ld_elem(bo, n0 + fm, f32m);
#pragma unroll
  for (int r = 0; r < 4; ++r) {
    size_t off0 = (size_t)(m0 + w * 32 + q * 4 + r) * 512 + n0 + fm;
    size_t off1 = off0 + (size_t)16 * 512;
    float v0 = acc0[r] + bias, v1 = acc1[r] + bias;
    if (f32m) { ((float*)Ybase)[off0] = v0; ((float*)Ybase)[off1] = v1; }
    else      { ((ushort_t*)Ybase)[off0] = f2b(v0); ((ushort_t*)Ybase)[off1] = f2b(v1); }
  }
}

extern "C" void kernel_launch(void* const* d_in, const int* in_sizes, int n_in,
                              void* d_out, int out_size, void* d_ws, size_t ws_size,
                              hipStream_t stream) {
  (void)in_sizes; (void)n_in; (void)out_size; (void)ws_size;
  const void* enc_inp = d_in[0];
  const void* dec_inp = d_in[1];
  const void* eWih = d_in[2];
  const void* eWhh = d_in[3];
  const void* ebih = d_in[4];
  const void* ebhh = d_in[5];
  const void* dWih = d_in[6];
  const void* dWhh = d_in[7];
  const void* dbih = d_in[8];
  const void* dbhh = d_in[9];
  const void* outW = d_in[10];
  const void* outb = d_in[11];

  unsigned* flag = (unsigned*)d_ws;

  // scratch inside the dec_outputs region of d_out (overwritten by out_proj):
  //   [0,128)        : go line
  //   [128, 128+16K) : 128 flag lines (128 B apart)
  //   [32K, 32K+256K): hbuf0 (bf16)   [+256K..]: hbuf1
  char* ob = (char*)d_out;
  unsigned* go = (unsigned*)ob;
  unsigned* flags = (unsigned*)(ob + 128);
  ushort_t* hbuf0 = (ushort_t*)(ob + 32768);
  ushort_t* hbuf1 = (ushort_t*)(ob + 32768 + (size_t)B * HD * 2);

  // zero go/flags/hbuf0 (initial h = 0); hbuf1 fully written at step 0
  hipMemsetAsync(d_out, 0, 32768 + (size_t)B * HD * 2, stream);

  detect<<<1, 64, 0, stream>>>((const ushort_t*)eWhh, flag);
  lstm_seq<<<GG, NT, 0, stream>>>(enc_inp, dec_inp, eWih, eWhh, ebih, ebhh,
                                  dWih, dWhh, dbih, dbhh,
                                  hbuf0, hbuf1, flags, go, d_out, flag);
  out_proj<<<dim3(64 * 32), NT, 0, stream>>>(outW, outb, d_out, flag);
}